// Round 3
// baseline (311.657 us; speedup 1.0000x reference)
//
#include <hip/hip_runtime.h>

// SABR IV surface, BETA=1 specialization (price-independent output).
//
// R8: DIAGNOSTIC PROBE, intentionally slow. The sabr kernel has never
// appeared in the top-5 counter table (saturated by ~124-133us harness fill
// dispatches), so none of its own counters have ever been observed. This
// probe repeats the full compute+LDS+store pipeline REPS=5 times so the
// dispatch exceeds the ~124us visibility threshold in every candidate world:
//   - CSE across reps defeated by asm volatile("+v") on the vol value.
//   - Odd reps store to the 210MB workspace region (distinct memory ->
//     repeats cannot be coalesced/absorbed by L2/L3 same-line rewrites).
//   - Last rep (r=4, even) writes `out` with correct values -> passes.
// Read next round: probe dur_us, VALUBusy, WRITE_SIZE/hbm_gbps,
// OccupancyPercent, SQ_LDS_BANK_CONFLICT. Decision table in journal.

#define THREADS 256
#define VALS_PER_PAIR 25
#define WAVE 64
#define REPS 5

__device__ __forceinline__ float fast_ln(float x) {
    // v_log_f32 gives log2(x); scale by ln(2)
    return __builtin_amdgcn_logf(x) * 0.6931471805599453f;
}

__global__ __launch_bounds__(THREADS)
void sabr_probe(const float* __restrict__ vol, float* __restrict__ out,
                float* __restrict__ alt) {
    __shared__ float sm[THREADS * VALS_PER_PAIR];  // 25.6 KB

    const int tid   = threadIdx.x;
    const int wave  = tid >> 6;
    const int lane  = tid & 63;
    const int pair0 = blockIdx.x * THREADS;
    const float v   = vol[pair0 + tid];

    // wave-private LDS slice: 64 pairs * 25 vals = 1600 floats
    float* smw = sm + wave * (WAVE * VALS_PER_PAIR);

    const float c1 = -0.0525f;                       // RHO*VOLVOL/4
    const float c2 = 0.09f * 0.53f / 24.0f;          // VOLVOL^2*(2-3*RHO^2)/24
    // cPhi[m] = VOLVOL * (-log(m)); m = {0.7, 0.85, 1.0, 1.15, 1.3}
    const float cPhi[5] = { 0.3f * 0.35667494393873245f,
                            0.3f * 0.1625189294977749f,
                            0.0f,
                            0.3f * -0.13976194237515863f,
                            0.3f * -0.26236426446749106f };

    const size_t wbase = (size_t)(pair0 + wave * WAVE) * VALS_PER_PAIR;

#pragma unroll 1
    for (int r = 0; r < REPS; ++r) {
        float vs = v;
        asm volatile("" : "+v"(vs));   // opaque per-rep: defeats CSE/hoisting

        float g[5];
        const float inv_v = __builtin_amdgcn_rcpf(vs);
#pragma unroll
        for (int mi = 0; mi < 5; ++mi) {
            if (mi == 2) { g[2] = 1.0f; continue; }
            const float Phi = cPhi[mi] * inv_v;
            const float arg = (__builtin_amdgcn_sqrtf(1.0f + 1.4f * Phi + Phi * Phi)
                               + Phi + 0.7f) * (1.0f / 1.7f);
            const float Chi = fast_ln(arg);
            g[mi] = Phi * __builtin_amdgcn_rcpf(Chi + 1e-8f);
        }

        const float slope = c1 * vs + c2;
#pragma unroll
        for (int ti = 0; ti < 5; ++ti) {
            const float vB = vs * (1.0f + (float)ti * slope);
#pragma unroll
            for (int mi = 0; mi < 5; ++mi) {
                smw[lane * VALS_PER_PAIR + ti * 5 + mi] = vB * g[mi];
            }
        }
        // No barrier: wave-private slice; same-wave DS ops are in-order.

        // Even reps (incl. the final r=4) -> out (correct data every time).
        // Odd reps -> workspace (distinct memory, real HBM write traffic).
        float* dst = (r & 1) ? alt : out;
        float4* __restrict__ out4 = (float4*)(dst + wbase);
        const float4* __restrict__ sm4 = (const float4*)smw;
#pragma unroll
        for (int kk = 0; kk < 6; ++kk)
            out4[kk * WAVE + lane] = sm4[kk * WAVE + lane];
        if (lane < 16)
            out4[6 * WAVE + lane] = sm4[6 * WAVE + lane];
    }
}

extern "C" void kernel_launch(void* const* d_in, const int* in_sizes, int n_in,
                              void* d_out, int out_size, void* d_ws, size_t ws_size,
                              hipStream_t stream) {
    const float* vol = (const float*)d_in[0];
    // d_in[1] (price) unused: BETA=1, R=Q=0 -> output is price-independent.
    float* out = (float*)d_out;
    const int npair = in_sizes[0];          // 4096*512 = 2097152
    const size_t out_bytes = (size_t)npair * VALS_PER_PAIR * sizeof(float);
    // Odd-rep target: workspace if large enough, else fall back to out
    // (fallback degrades the probe but stays safe/correct).
    float* alt = (d_ws != nullptr && ws_size >= out_bytes) ? (float*)d_ws : out;
    const int grid = npair / THREADS;       // 8192 blocks
    sabr_probe<<<grid, THREADS, 0, stream>>>(vol, out, alt);
}

// Round 4
// 209.363 us; speedup vs baseline: 1.4886x; 1.4886x over previous
//
#include <hip/hip_runtime.h>

// SABR IV surface, specialized for BETA=1, R=Q=0, RHO=-0.7, VOLVOL=0.3.
// With BETA=1: x=1, A=v, F=p, logFK=-log(m) -> output independent of price.
// out[i,j,t,m] = v*B(t)                      if m==1.0
//              = v*B(t)*Phi(m)/(Chi(m)+1e-8) otherwise
// B(t) = 1 + t*(c1*v + c2), Phi = 0.3*(-log m)/v,
// Chi = log((sqrt(1 + 1.4*Phi + Phi^2) + Phi + 0.7)/1.7)
//
// R9 (final): restore R7 (session best, 209.1us). R8's REPS=5 probe proved
// the kernel itself runs at ~25us/rep marginal and <38us single-shot
// (probe(5 reps) stayed below the 140.7us top-5 cutoff -> fixed part <13us),
// i.e. AT the 218MB/5.9-6.3TB/s write-traffic floor (~33-37us). The rest of
// dur_us is the harness poison fill (~125-145us) plus ~40-50us of
// harness-side work outside this kernel. No kernel-addressable gap remains:
// write-BW roofline reached.

#define THREADS 256
#define BATCH 4
#define VALS_PER_PAIR 25
#define WAVE 64

__device__ __forceinline__ float fast_ln(float x) {
    // v_log_f32 gives log2(x); scale by ln(2)
    return __builtin_amdgcn_logf(x) * 0.6931471805599453f;
}

__global__ __launch_bounds__(THREADS, 4)
void sabr_kernel(const float* __restrict__ vol, float* __restrict__ out) {
    __shared__ float sm[THREADS * VALS_PER_PAIR];  // 25.6 KB

    const int tid   = threadIdx.x;
    const int wave  = tid >> 6;
    const int lane  = tid & 63;
    const int base  = blockIdx.x * (THREADS * BATCH);

    // Issue all BATCH loads up-front: one HBM latency exposure, coalesced.
    float v[BATCH];
#pragma unroll
    for (int s = 0; s < BATCH; ++s)
        v[s] = vol[base + s * THREADS + tid];

    // wave-private LDS slice: 64 pairs * 25 vals = 1600 floats
    float* smw = sm + wave * (WAVE * VALS_PER_PAIR);

    // Constants
    const float c1 = -0.0525f;                       // RHO*VOLVOL/4
    const float c2 = 0.09f * 0.53f / 24.0f;          // VOLVOL^2*(2-3*RHO^2)/24
    // cPhi[m] = VOLVOL * (-log(m)); m = {0.7, 0.85, 1.0, 1.15, 1.3}
    const float cPhi[5] = { 0.3f * 0.35667494393873245f,
                            0.3f * 0.1625189294977749f,
                            0.0f,
                            0.3f * -0.13976194237515863f,
                            0.3f * -0.26236426446749106f };

#pragma unroll
    for (int s = 0; s < BATCH; ++s) {
        const float vs = v[s];

        float g[5];
        const float inv_v = __builtin_amdgcn_rcpf(vs);
#pragma unroll
        for (int mi = 0; mi < 5; ++mi) {
            if (mi == 2) { g[2] = 1.0f; continue; }
            const float Phi = cPhi[mi] * inv_v;
            const float arg = (__builtin_amdgcn_sqrtf(1.0f + 1.4f * Phi + Phi * Phi)
                               + Phi + 0.7f) * (1.0f / 1.7f);
            const float Chi = fast_ln(arg);
            g[mi] = Phi * __builtin_amdgcn_rcpf(Chi + 1e-8f);
        }

        const float slope = c1 * vs + c2;
#pragma unroll
        for (int ti = 0; ti < 5; ++ti) {
            const float vB = vs * (1.0f + (float)ti * slope);
#pragma unroll
            for (int mi = 0; mi < 5; ++mi) {
                smw[lane * VALS_PER_PAIR + ti * 5 + mi] = vB * g[mi];
            }
        }
        // No barrier: wave reads only its own slice; same-wave DS ops are
        // processed in order, so batch s reads complete before batch s+1
        // writes land, and the compiler's lgkmcnt orders writes->reads.

        // Wave's output range for this sub-batch: 64*25 = 1600 floats
        float4* __restrict__ out4 =
            (float4*)(out + (size_t)(base + s * THREADS + wave * WAVE) * VALS_PER_PAIR);
        const float4* __restrict__ sm4 = (const float4*)smw;
#pragma unroll
        for (int kk = 0; kk < 6; ++kk)
            out4[kk * WAVE + lane] = sm4[kk * WAVE + lane];
        if (lane < 16)
            out4[6 * WAVE + lane] = sm4[6 * WAVE + lane];
    }
}

extern "C" void kernel_launch(void* const* d_in, const int* in_sizes, int n_in,
                              void* d_out, int out_size, void* d_ws, size_t ws_size,
                              hipStream_t stream) {
    const float* vol = (const float*)d_in[0];
    // d_in[1] (price) is unused: with BETA=1 and R=Q=0 the output is price-independent.
    float* out = (float*)d_out;
    const int npair = in_sizes[0];              // 4096*512 = 2097152
    const int grid  = npair / (THREADS * BATCH); // 2048 blocks
    sabr_kernel<<<grid, THREADS, 0, stream>>>(vol, out);
}